// Round 2
// baseline (5945.016 us; speedup 1.0000x reference)
//
#include <hip/hip_runtime.h>
#include <stdint.h>

typedef short short8 __attribute__((ext_vector_type(8)));
typedef float f32x4 __attribute__((ext_vector_type(4)));
typedef float f32x2 __attribute__((ext_vector_type(2)));
typedef unsigned long long u64;

#define TSEQ   128
#define BATCH  64
#define DIM    512
#define HID    1024
#define G3     3072
#define MROWS  (TSEQ * BATCH)   // 8192
#define NB     32               // gru grid (blocks)
#define HB     32               // hidden units per gru block

__device__ __forceinline__ unsigned short f2bf(float f) {
  union { float f; unsigned u; } v; v.f = f;
  unsigned u = v.u;
  return (unsigned short)((u + 0x7FFFu + ((u >> 16) & 1u)) >> 16);
}

__device__ __forceinline__ short8 pack8(f32x4 a, f32x4 b) {
  short8 r;
  r[0] = (short)f2bf(a.x); r[1] = (short)f2bf(a.y);
  r[2] = (short)f2bf(a.z); r[3] = (short)f2bf(a.w);
  r[4] = (short)f2bf(b.x); r[5] = (short)f2bf(b.y);
  r[6] = (short)f2bf(b.z); r[7] = (short)f2bf(b.w);
  return r;
}

__device__ __forceinline__ u64 packbf4(float a, float b, float c, float d) {
  return (u64)f2bf(a) | ((u64)f2bf(b) << 16) | ((u64)f2bf(c) << 32) | ((u64)f2bf(d) << 48);
}

__device__ __forceinline__ short8 mk8(u64 lo, u64 hi) {
  union { u64 q[2]; short8 s; } uu; uu.q[0] = lo; uu.q[1] = hi; return uu.s;
}

// agent-scope (device-coherent, cross-XCD via IF) relaxed atomics — no L2 wbl2/inv
__device__ __forceinline__ u64 ald(const u64* p) {
  return __hip_atomic_load(p, __ATOMIC_RELAXED, __HIP_MEMORY_SCOPE_AGENT);
}
__device__ __forceinline__ void ast(u64* p, u64 v) {
  __hip_atomic_store(p, v, __ATOMIC_RELAXED, __HIP_MEMORY_SCOPE_AGENT);
}

__device__ __forceinline__ float sigm(float x) { return 1.0f / (1.0f + __expf(-x)); }
__device__ __forceinline__ float tanh_fast(float x) { return 2.0f / (1.0f + __expf(-2.0f * x)) - 1.0f; }

// ---------------- prep: gather emb rows + convert Wih to bf16 + zero barriers ----------------
__global__ __launch_bounds__(256) void prep_kernel(
    const int* __restrict__ ids, const float* __restrict__ emb,
    const float* __restrict__ wih, unsigned short* __restrict__ X,
    unsigned short* __restrict__ Wb, unsigned int* bars, int nbar)
{
  int row = blockIdx.x;
  int tid = threadIdx.x;
  const float* srcp;
  unsigned short* dst;
  if (row < MROWS) {
    srcp = emb + (long)ids[row] * DIM;
    dst  = X + (long)row * DIM;
  } else {
    int wr = row - MROWS;
    srcp = wih + (long)wr * DIM;
    dst  = Wb + (long)wr * DIM;
  }
  int d = tid * 2;
  f32x2 v = *(const f32x2*)(srcp + d);
  unsigned pk = (unsigned)f2bf(v.x) | ((unsigned)f2bf(v.y) << 16);
  *(unsigned*)(dst + d) = pk;
  if (bars != nullptr && row == 0 && tid < nbar) bars[tid] = 0u;
}

// ---------------- xW GEMM: C[m][n] = sum_k X[m][k]*W[n][k] + bih[n] ----------------
#define BM 128
#define BN 128
#define BK 32

__global__ __launch_bounds__(256) void xw_gemm(
    const unsigned short* __restrict__ X,   // [8192][512] bf16
    const unsigned short* __restrict__ W,   // [3072][512] bf16
    const float* __restrict__ bih,          // [3072]
    float* __restrict__ out)                // [8192][3072] f32
{
  __shared__ unsigned short As[BM * BK];
  __shared__ unsigned short Bs[BN * BK];
  int tid = threadIdx.x;
  int w = tid >> 6, l = tid & 63;
  int m0 = blockIdx.y * BM;
  int n0 = blockIdx.x * BN;
  int wr = w >> 1, wc = w & 1;

  int sr = tid >> 2, skq = tid & 3;
  int sr2 = sr + 64;
  int sgk  = (skq - (sr  >> 1)) & 3;
  int sgk2 = (skq - (sr2 >> 1)) & 3;
  const unsigned short* gA0 = X + (long)(m0 + sr ) * DIM + sgk  * 8;
  const unsigned short* gA1 = X + (long)(m0 + sr2) * DIM + sgk2 * 8;
  const unsigned short* gB0 = W + (long)(n0 + sr ) * DIM + sgk  * 8;
  const unsigned short* gB1 = W + (long)(n0 + sr2) * DIM + sgk2 * 8;
  unsigned short* lA0 = As + sr  * BK + skq * 8;
  unsigned short* lA1 = As + sr2 * BK + skq * 8;
  unsigned short* lB0 = Bs + sr  * BK + skq * 8;
  unsigned short* lB1 = Bs + sr2 * BK + skq * 8;

  f32x4 acc[4][4];
  #pragma unroll
  for (int mt = 0; mt < 4; ++mt)
    #pragma unroll
    for (int nt = 0; nt < 4; ++nt) acc[mt][nt] = (f32x4){};

  short8 va0 = *(const short8*)(gA0);
  short8 va1 = *(const short8*)(gA1);
  short8 vb0 = *(const short8*)(gB0);
  short8 vb1 = *(const short8*)(gB1);

  int fr = l & 15, fk = l >> 4;
  for (int kt = 0; kt < DIM / BK; ++kt) {
    __syncthreads();
    *(short8*)lA0 = va0; *(short8*)lA1 = va1;
    *(short8*)lB0 = vb0; *(short8*)lB1 = vb1;
    __syncthreads();
    if (kt + 1 < DIM / BK) {
      int ko = (kt + 1) * BK;
      va0 = *(const short8*)(gA0 + ko);
      va1 = *(const short8*)(gA1 + ko);
      vb0 = *(const short8*)(gB0 + ko);
      vb1 = *(const short8*)(gB1 + ko);
    }
    short8 af[4], bf[4];
    #pragma unroll
    for (int mt = 0; mt < 4; ++mt) {
      int r = wr * 64 + mt * 16 + fr;
      int slot = ((r >> 1) + fk) & 3;
      af[mt] = *(const short8*)(As + r * BK + slot * 8);
    }
    #pragma unroll
    for (int nt = 0; nt < 4; ++nt) {
      int r = wc * 64 + nt * 16 + fr;
      int slot = ((r >> 1) + fk) & 3;
      bf[nt] = *(const short8*)(Bs + r * BK + slot * 8);
    }
    #pragma unroll
    for (int mt = 0; mt < 4; ++mt)
      #pragma unroll
      for (int nt = 0; nt < 4; ++nt)
        acc[mt][nt] = __builtin_amdgcn_mfma_f32_16x16x32_bf16(af[mt], bf[nt], acc[mt][nt], 0, 0, 0);
  }

  #pragma unroll
  for (int nt = 0; nt < 4; ++nt) {
    int n = n0 + wc * 64 + nt * 16 + fr;
    float bias = bih[n];
    #pragma unroll
    for (int mt = 0; mt < 4; ++mt) {
      int mbase = m0 + wr * 64 + mt * 16 + fk * 4;
      #pragma unroll
      for (int r = 0; r < 4; ++r)
        out[(long)(mbase + r) * G3 + n] = acc[mt][nt][r] + bias;
    }
  }
}

// ---------------- persistent masked GRU ----------------
// Transposed matvec: C[m][n] = sum_k Whh_rows[m][k] * h[n][k]
// Block owns HB=32 units -> 96 gate rows. 4 waves: (mm = row-half 0/1) x (km = K-half 0/1).
// Weights in registers (areg[3][16] = 192 VGPR). h exchanged via agent-scope (sc1)
// atomics through the Infinity Cache — no L2 fences anywhere.
__global__ __launch_bounds__(256, 1) void gru_kernel(
    const float* __restrict__ Whh, const float* __restrict__ bhh,
    const float* __restrict__ xw, const int* __restrict__ lengths,
    u64* __restrict__ hbf,            // [2][BATCH][HID/4] u64 (4 bf16 each)
    float* __restrict__ hf32,         // [BATCH][HID]
    unsigned int* __restrict__ bar, int T, int initzero)
{
  const int tid = threadIdx.x;
  const int w = tid >> 6, l = tid & 63;
  const int fr = l & 15, fk = l >> 4;
  const int km = w & 1, mm = w >> 1;
  const int U0 = blockIdx.x * HB;

  // ---- Whh fragments -> registers: wave (mm,km) holds rows mm*48..+47, K half km*512..+511 ----
  short8 areg[3][16];
  #pragma unroll
  for (int mt = 0; mt < 3; ++mt) {
    const int m = mm * 48 + mt * 16 + fr;          // 0..95
    const int gate = m >> 5, u = m & 31;
    const float* wp = Whh + (size_t)(gate * HID + U0 + u) * HID + km * 512 + fk * 8;
    #pragma unroll
    for (int ksl = 0; ksl < 16; ++ksl) {
      f32x4 a0 = *(const f32x4*)(wp + ksl * 32);
      f32x4 a1 = *(const f32x4*)(wp + ksl * 32 + 4);
      areg[mt][ksl] = pack8(a0, a1);
    }
  }

  // ---- gate-phase ownership: batch gb = lane, units j0..j0+7 (j0 = wave*8) ----
  const int gb = l;
  const int j0 = w * 8;
  const size_t hoff = (size_t)gb * (HID / 4) + (size_t)(U0 + j0) / 4;  // in u64 units
  const int len_b = lengths[gb];

  float h[8];
  #pragma unroll
  for (int j = 0; j < 8; ++j)
    h[j] = initzero ? 0.0f : hf32[(size_t)gb * HID + U0 + j0 + j];

  float br[8], bz[8], bn[8];
  #pragma unroll
  for (int j = 0; j < 8; ++j) {
    br[j] = bhh[U0 + j0 + j];
    bz[j] = bhh[HID + U0 + j0 + j];
    bn[j] = bhh[2 * HID + U0 + j0 + j];
  }

  __shared__ float red[2][96][67];   // 51 KB; [km][gate-row][batch]

  f32x4 xrv[2], xzv[2], xnv[2];
  #define LOAD_XW(tt) do { \
    const float* xp_ = xw + ((size_t)(tt) * BATCH + gb) * G3 + U0 + j0; \
    xrv[0] = *(const f32x4*)(xp_);            xrv[1] = *(const f32x4*)(xp_ + 4); \
    xzv[0] = *(const f32x4*)(xp_ + HID);      xzv[1] = *(const f32x4*)(xp_ + HID + 4); \
    xnv[0] = *(const f32x4*)(xp_ + 2 * HID);  xnv[1] = *(const f32x4*)(xp_ + 2 * HID + 4); \
  } while (0)

  // ---- publish h(0) into buffer 0, then barrier gen 1 ----
  {
    u64 plo = packbf4(h[0], h[1], h[2], h[3]);
    u64 phi = packbf4(h[4], h[5], h[6], h[7]);
    ast(hbf + hoff, plo);
    ast(hbf + hoff + 1, phi);
    asm volatile("s_waitcnt vmcnt(0)" ::: "memory");
    __syncthreads();
    if (tid == 0) {
      unsigned prev = __hip_atomic_fetch_add(bar, 1u, __ATOMIC_RELAXED, __HIP_MEMORY_SCOPE_AGENT);
      if (prev == (unsigned)NB - 1u)
        __hip_atomic_store(bar + 16, 1u, __ATOMIC_RELAXED, __HIP_MEMORY_SCOPE_AGENT);
    }
    LOAD_XW(0);
    if (tid == 0) {
      while (__hip_atomic_load(bar + 16, __ATOMIC_RELAXED, __HIP_MEMORY_SCOPE_AGENT) < 1u)
        __builtin_amdgcn_s_sleep(2);
    }
    __syncthreads();
  }

  for (int t = 0; t < T; ++t) {
    const u64* hb = hbf + (size_t)(t & 1) * (BATCH * (HID / 4));

    f32x4 acc[3][4];
    #pragma unroll
    for (int mt = 0; mt < 3; ++mt)
      #pragma unroll
      for (int nt = 0; nt < 4; ++nt) acc[mt][nt] = (f32x4){};

    #pragma unroll
    for (int ksl = 0; ksl < 16; ++ksl) {
      const int kb = km * 128 + ksl * 8 + fk * 2;
      #pragma unroll
      for (int nt = 0; nt < 4; ++nt) {
        const u64* bp = hb + (size_t)(nt * 16 + fr) * (HID / 4) + kb;
        u64 lo = ald(bp);
        u64 hi = ald(bp + 1);
        short8 bf = mk8(lo, hi);
        acc[0][nt] = __builtin_amdgcn_mfma_f32_16x16x32_bf16(areg[0][ksl], bf, acc[0][nt], 0, 0, 0);
        acc[1][nt] = __builtin_amdgcn_mfma_f32_16x16x32_bf16(areg[1][ksl], bf, acc[1][nt], 0, 0, 0);
        acc[2][nt] = __builtin_amdgcn_mfma_f32_16x16x32_bf16(areg[2][ksl], bf, acc[2][nt], 0, 0, 0);
      }
    }

    // cross-wave K reduce via LDS
    #pragma unroll
    for (int mt = 0; mt < 3; ++mt)
      #pragma unroll
      for (int nt = 0; nt < 4; ++nt)
        #pragma unroll
        for (int r = 0; r < 4; ++r)
          red[km][mm * 48 + mt * 16 + fk * 4 + r][nt * 16 + fr] = acc[mt][nt][r];
    __syncthreads();

    const int upd = (t < len_b);
    #pragma unroll
    for (int j = 0; j < 8; ++j) {
      const int u = j0 + j;
      float hrv = red[0][u][gb]      + red[1][u][gb]      + br[j];
      float hzv = red[0][32 + u][gb] + red[1][32 + u][gb] + bz[j];
      float hnv = red[0][64 + u][gb] + red[1][64 + u][gb] + bn[j];
      float rr = sigm(xrv[j >> 2][j & 3] + hrv);
      float zz = sigm(xzv[j >> 2][j & 3] + hzv);
      float nn = tanh_fast(xnv[j >> 2][j & 3] + rr * hnv);
      float cc = (1.0f - zz) * nn + zz * h[j];
      h[j] = upd ? cc : h[j];
    }

    if (t + 1 < T) {
      u64 plo = packbf4(h[0], h[1], h[2], h[3]);
      u64 phi = packbf4(h[4], h[5], h[6], h[7]);
      u64* hw = hbf + (size_t)((t + 1) & 1) * (BATCH * (HID / 4)) + hoff;
      ast(hw, plo);
      ast(hw + 1, phi);
      asm volatile("s_waitcnt vmcnt(0)" ::: "memory");   // h stores acked at coherent point
      __syncthreads();                                    // all waves' stores done
      if (tid == 0) {
        unsigned prev = __hip_atomic_fetch_add(bar, 1u, __ATOMIC_RELAXED, __HIP_MEMORY_SCOPE_AGENT);
        if (prev == (unsigned)(t + 2) * (unsigned)NB - 1u)
          __hip_atomic_store(bar + 16, (unsigned)(t + 2), __ATOMIC_RELAXED, __HIP_MEMORY_SCOPE_AGENT);
      }
      LOAD_XW(t + 1);   // prefetch next step's gate inputs under the barrier wait
      if (tid == 0) {
        while (__hip_atomic_load(bar + 16, __ATOMIC_RELAXED, __HIP_MEMORY_SCOPE_AGENT) < (unsigned)(t + 2))
          __builtin_amdgcn_s_sleep(2);
      }
      __syncthreads();
    }
  }

  #pragma unroll
  for (int j = 0; j < 8; ++j)
    hf32[(size_t)gb * HID + U0 + j0 + j] = h[j];
}

// ---------------- head: logits = tanh(h @ p1^T + b1) @ p2^T + b2 ----------------
__global__ __launch_bounds__(256) void head_kernel(
    const float* __restrict__ hf32, const float* __restrict__ p1W,
    const float* __restrict__ p1b, const float* __restrict__ p2W,
    const float* __restrict__ p2b, float* __restrict__ outp)
{
  int b = blockIdx.x;
  int tid = threadIdx.x;
  __shared__ float hrow[HID];
  __shared__ float red[4][64];
  __shared__ float s1[64];
  for (int d = tid; d < HID; d += 256) hrow[d] = hf32[(long)b * HID + d];
  __syncthreads();
  int j = tid & 63, q = tid >> 6;
  const float* wrow = p1W + (long)j * HID + q * 256;
  float s = 0.0f;
  for (int k = 0; k < 256; ++k) s += hrow[q * 256 + k] * wrow[k];
  red[q][j] = s;
  __syncthreads();
  if (tid < 64) {
    float v = red[0][tid] + red[1][tid] + red[2][tid] + red[3][tid] + p1b[tid];
    s1[tid] = tanh_fast(v);
  }
  __syncthreads();
  if (tid < 2) {
    float a = p2b[tid];
    for (int k = 0; k < 64; ++k) a += s1[k] * p2W[tid * 64 + k];
    outp[b * 2 + tid] = a;
  }
}

// ---------------- launch ----------------
extern "C" void kernel_launch(void* const* d_in, const int* in_sizes, int n_in,
                              void* d_out, int out_size, void* d_ws, size_t ws_size,
                              hipStream_t stream) {
  const int*   tgt_ids = (const int*)d_in[0];
  const int*   tgt_len = (const int*)d_in[1];
  const int*   src_ids = (const int*)d_in[2];
  const int*   src_len = (const int*)d_in[3];
  const float* emb  = (const float*)d_in[6];
  const float* sWih = (const float*)d_in[7];
  const float* sWhh = (const float*)d_in[8];
  const float* sbih = (const float*)d_in[9];
  const float* sbhh = (const float*)d_in[10];
  const float* tWih = (const float*)d_in[11];
  const float* tWhh = (const float*)d_in[12];
  const float* tbih = (const float*)d_in[13];
  const float* tbhh = (const float*)d_in[14];
  const float* p1W  = (const float*)d_in[19];
  const float* p1b  = (const float*)d_in[20];
  const float* p2W  = (const float*)d_in[21];
  const float* p2b  = (const float*)d_in[22];

  char* ws = (char*)d_ws;
  size_t off = 0;
  float* xw = (float*)(ws + off);                   off += (size_t)MROWS * G3 * 4;
  unsigned short* X  = (unsigned short*)(ws + off); off += (size_t)MROWS * DIM * 2;
  unsigned short* Wb = (unsigned short*)(ws + off); off += (size_t)G3 * DIM * 2;
  u64* hbf = (u64*)(ws + off);                      off += 2ull * BATCH * (HID / 4) * 8;
  float* hf32 = (float*)(ws + off);                 off += (size_t)BATCH * HID * 4;
  unsigned int* bars = (unsigned int*)(ws + off);   off += 256;
  if (ws_size < off) return;

  const int PREP_BLOCKS = MROWS + G3;  // 11264

  // src pipeline
  prep_kernel<<<PREP_BLOCKS, 256, 0, stream>>>(src_ids, emb, sWih, X, Wb, bars, 64);
  xw_gemm<<<dim3(G3 / BN, MROWS / BM), 256, 0, stream>>>(X, Wb, sbih, xw);
  gru_kernel<<<NB, 256, 0, stream>>>(sWhh, sbhh, xw, src_len, hbf, hf32, bars, TSEQ, 1);
  // tgt pipeline (h0 = src final hidden in hf32)
  prep_kernel<<<PREP_BLOCKS, 256, 0, stream>>>(tgt_ids, emb, tWih, X, Wb, nullptr, 0);
  xw_gemm<<<dim3(G3 / BN, MROWS / BM), 256, 0, stream>>>(X, Wb, tbih, xw);
  gru_kernel<<<NB, 256, 0, stream>>>(tWhh, tbhh, xw, tgt_len, hbf, hf32, bars + 32, TSEQ, 0);
  // head
  head_kernel<<<BATCH, 256, 0, stream>>>(hf32, p1W, p1b, p2W, p2b, (float*)d_out);
}

// Round 3
// 2963.996 us; speedup vs baseline: 2.0057x; 2.0057x over previous
//
#include <hip/hip_runtime.h>
#include <stdint.h>

typedef short short8 __attribute__((ext_vector_type(8)));
typedef float f32x4 __attribute__((ext_vector_type(4)));
typedef float f32x2 __attribute__((ext_vector_type(2)));
typedef unsigned long long u64;

#define TSEQ   128
#define BATCH  64
#define DIM    512
#define HID    1024
#define G3     3072
#define MROWS  (TSEQ * BATCH)   // 8192
#define NB     32               // gru grid (blocks)
#define HB     32               // hidden units per gru block

__device__ __forceinline__ unsigned short f2bf(float f) {
  union { float f; unsigned u; } v; v.f = f;
  unsigned u = v.u;
  return (unsigned short)((u + 0x7FFFu + ((u >> 16) & 1u)) >> 16);
}

__device__ __forceinline__ short8 pack8(f32x4 a, f32x4 b) {
  short8 r;
  r[0] = (short)f2bf(a.x); r[1] = (short)f2bf(a.y);
  r[2] = (short)f2bf(a.z); r[3] = (short)f2bf(a.w);
  r[4] = (short)f2bf(b.x); r[5] = (short)f2bf(b.y);
  r[6] = (short)f2bf(b.z); r[7] = (short)f2bf(b.w);
  return r;
}

__device__ __forceinline__ u64 packbf4(float a, float b, float c, float d) {
  return (u64)f2bf(a) | ((u64)f2bf(b) << 16) | ((u64)f2bf(c) << 32) | ((u64)f2bf(d) << 48);
}

__device__ __forceinline__ float sigm(float x) { return 1.0f / (1.0f + __expf(-x)); }
__device__ __forceinline__ float tanh_fast(float x) { return 2.0f / (1.0f + __expf(-2.0f * x)) - 1.0f; }

// ---------------- prep: gather emb rows + convert Wih to bf16 + zero barriers ----------------
__global__ __launch_bounds__(256) void prep_kernel(
    const int* __restrict__ ids, const float* __restrict__ emb,
    const float* __restrict__ wih, unsigned short* __restrict__ X,
    unsigned short* __restrict__ Wb, unsigned int* bars, int nbar)
{
  int row = blockIdx.x;
  int tid = threadIdx.x;
  const float* srcp;
  unsigned short* dst;
  if (row < MROWS) {
    srcp = emb + (long)ids[row] * DIM;
    dst  = X + (long)row * DIM;
  } else {
    int wr = row - MROWS;
    srcp = wih + (long)wr * DIM;
    dst  = Wb + (long)wr * DIM;
  }
  int d = tid * 2;
  f32x2 v = *(const f32x2*)(srcp + d);
  unsigned pk = (unsigned)f2bf(v.x) | ((unsigned)f2bf(v.y) << 16);
  *(unsigned*)(dst + d) = pk;
  if (bars != nullptr && row == 0 && tid < nbar) bars[tid] = 0u;
}

// ---------------- xW GEMM: C[m][n] = sum_k X[m][k]*W[n][k] + bih[n] ----------------
#define BM 128
#define BN 128
#define BK 32

__global__ __launch_bounds__(256) void xw_gemm(
    const unsigned short* __restrict__ X,   // [8192][512] bf16
    const unsigned short* __restrict__ W,   // [3072][512] bf16
    const float* __restrict__ bih,          // [3072]
    float* __restrict__ out)                // [8192][3072] f32
{
  __shared__ unsigned short As[BM * BK];
  __shared__ unsigned short Bs[BN * BK];
  int tid = threadIdx.x;
  int w = tid >> 6, l = tid & 63;
  int m0 = blockIdx.y * BM;
  int n0 = blockIdx.x * BN;
  int wr = w >> 1, wc = w & 1;

  int sr = tid >> 2, skq = tid & 3;
  int sr2 = sr + 64;
  int sgk  = (skq - (sr  >> 1)) & 3;
  int sgk2 = (skq - (sr2 >> 1)) & 3;
  const unsigned short* gA0 = X + (long)(m0 + sr ) * DIM + sgk  * 8;
  const unsigned short* gA1 = X + (long)(m0 + sr2) * DIM + sgk2 * 8;
  const unsigned short* gB0 = W + (long)(n0 + sr ) * DIM + sgk  * 8;
  const unsigned short* gB1 = W + (long)(n0 + sr2) * DIM + sgk2 * 8;
  unsigned short* lA0 = As + sr  * BK + skq * 8;
  unsigned short* lA1 = As + sr2 * BK + skq * 8;
  unsigned short* lB0 = Bs + sr  * BK + skq * 8;
  unsigned short* lB1 = Bs + sr2 * BK + skq * 8;

  f32x4 acc[4][4];
  #pragma unroll
  for (int mt = 0; mt < 4; ++mt)
    #pragma unroll
    for (int nt = 0; nt < 4; ++nt) acc[mt][nt] = (f32x4){};

  short8 va0 = *(const short8*)(gA0);
  short8 va1 = *(const short8*)(gA1);
  short8 vb0 = *(const short8*)(gB0);
  short8 vb1 = *(const short8*)(gB1);

  int fr = l & 15, fk = l >> 4;
  for (int kt = 0; kt < DIM / BK; ++kt) {
    __syncthreads();
    *(short8*)lA0 = va0; *(short8*)lA1 = va1;
    *(short8*)lB0 = vb0; *(short8*)lB1 = vb1;
    __syncthreads();
    if (kt + 1 < DIM / BK) {
      int ko = (kt + 1) * BK;
      va0 = *(const short8*)(gA0 + ko);
      va1 = *(const short8*)(gA1 + ko);
      vb0 = *(const short8*)(gB0 + ko);
      vb1 = *(const short8*)(gB1 + ko);
    }
    short8 af[4], bf[4];
    #pragma unroll
    for (int mt = 0; mt < 4; ++mt) {
      int r = wr * 64 + mt * 16 + fr;
      int slot = ((r >> 1) + fk) & 3;
      af[mt] = *(const short8*)(As + r * BK + slot * 8);
    }
    #pragma unroll
    for (int nt = 0; nt < 4; ++nt) {
      int r = wc * 64 + nt * 16 + fr;
      int slot = ((r >> 1) + fk) & 3;
      bf[nt] = *(const short8*)(Bs + r * BK + slot * 8);
    }
    #pragma unroll
    for (int mt = 0; mt < 4; ++mt)
      #pragma unroll
      for (int nt = 0; nt < 4; ++nt)
        acc[mt][nt] = __builtin_amdgcn_mfma_f32_16x16x32_bf16(af[mt], bf[nt], acc[mt][nt], 0, 0, 0);
  }

  #pragma unroll
  for (int nt = 0; nt < 4; ++nt) {
    int n = n0 + wc * 64 + nt * 16 + fr;
    float bias = bih[n];
    #pragma unroll
    for (int mt = 0; mt < 4; ++mt) {
      int mbase = m0 + wr * 64 + mt * 16 + fk * 4;
      #pragma unroll
      for (int r = 0; r < 4; ++r)
        out[(long)(mbase + r) * G3 + n] = acc[mt][nt][r] + bias;
    }
  }
}

// ---------------- persistent masked GRU ----------------
// Same work split & coherence protocol as the (passing) round-2 kernel:
//   - h exchanged through IF-coherent (sc0 sc1) accesses, double-buffered
//   - arrival counter at IF; spin on counter value directly
// Change: B-operand loads are inline-asm global_load_dwordx4 sc0 sc1 in a
// 3-group software pipeline with counted vmcnt — restores MLP the atomic
// loads destroyed.
#define MF(a, b, c) __builtin_amdgcn_mfma_f32_16x16x32_bf16(a, b, c, 0, 0, 0)

#define ISSUE(ss, kk) do { \
  asm volatile("global_load_dwordx4 %0, %1, off offset:%2 sc0 sc1" \
               : "=v"(bv[ss][0]) : "v"(ad0), "i"((kk) * 64) : "memory"); \
  asm volatile("global_load_dwordx4 %0, %1, off offset:%2 sc0 sc1" \
               : "=v"(bv[ss][1]) : "v"(ad1), "i"((kk) * 64) : "memory"); \
  asm volatile("global_load_dwordx4 %0, %1, off offset:%2 sc0 sc1" \
               : "=v"(bv[ss][2]) : "v"(ad2), "i"((kk) * 64) : "memory"); \
  asm volatile("global_load_dwordx4 %0, %1, off offset:%2 sc0 sc1" \
               : "=v"(bv[ss][3]) : "v"(ad3), "i"((kk) * 64) : "memory"); \
} while (0)

#define MF3(kk, ss, nt) \
  acc[0][nt] = MF(areg[0][kk], bv[ss][nt], acc[0][nt]); \
  acc[1][nt] = MF(areg[1][kk], bv[ss][nt], acc[1][nt]); \
  acc[2][nt] = MF(areg[2][kk], bv[ss][nt], acc[2][nt]);

#define KSTEP(kk, ss, wn) do { \
  asm volatile("s_waitcnt vmcnt(" #wn ")" ::: "memory"); \
  __builtin_amdgcn_sched_barrier(0); \
  MF3(kk, ss, 0) MF3(kk, ss, 1) MF3(kk, ss, 2) MF3(kk, ss, 3) \
} while (0)

#define KSTEPI(kk, ss, wn) do { KSTEP(kk, ss, wn); ISSUE(ss, (kk) + 3); } while (0)

__global__ __launch_bounds__(256, 1) void gru_kernel(
    const float* __restrict__ Whh, const float* __restrict__ bhh,
    const float* __restrict__ xw, const int* __restrict__ lengths,
    u64* __restrict__ hbf,            // [2][BATCH][HID/4] u64 (4 bf16 each)
    float* __restrict__ hf32,         // [BATCH][HID]
    unsigned int* __restrict__ bar, int T, int initzero)
{
  const int tid = threadIdx.x;
  const int w = tid >> 6, l = tid & 63;
  const int fr = l & 15, fk = l >> 4;
  const int km = w & 1, mm = w >> 1;
  const int U0 = blockIdx.x * HB;

  // ---- Whh fragments -> registers: wave (mm,km) holds rows mm*48..+47, K half km*512..+511 ----
  short8 areg[3][16];
  #pragma unroll
  for (int mt = 0; mt < 3; ++mt) {
    const int m = mm * 48 + mt * 16 + fr;          // 0..95
    const int gate = m >> 5, u = m & 31;
    const float* wp = Whh + (size_t)(gate * HID + U0 + u) * HID + km * 512 + fk * 8;
    #pragma unroll
    for (int ksl = 0; ksl < 16; ++ksl) {
      f32x4 a0 = *(const f32x4*)(wp + ksl * 32);
      f32x4 a1 = *(const f32x4*)(wp + ksl * 32 + 4);
      areg[mt][ksl] = pack8(a0, a1);
    }
  }

  // ---- gate-phase ownership: batch gb = lane, units j0..j0+7 (j0 = wave*8) ----
  const int gb = l;
  const int j0 = w * 8;
  const size_t hoff = (size_t)gb * (HID / 4) + (size_t)(U0 + j0) / 4;  // u64 units
  const int len_b = lengths[gb];

  float h[8];
  #pragma unroll
  for (int j = 0; j < 8; ++j)
    h[j] = initzero ? 0.0f : hf32[(size_t)gb * HID + U0 + j0 + j];

  __shared__ float red[2][96][67];   // 51 KB; [km][gate-row][batch]
  __shared__ float bb[3][32];        // biases for this block's 32 units x 3 gates
  if (tid < 96) bb[tid >> 5][tid & 31] = bhh[(tid >> 5) * HID + U0 + (tid & 31)];

  f32x4 xrv[2], xzv[2], xnv[2];
  #define LOAD_XW(tt) do { \
    const float* xp_ = xw + ((size_t)(tt) * BATCH + gb) * G3 + U0 + j0; \
    xrv[0] = *(const f32x4*)(xp_);            xrv[1] = *(const f32x4*)(xp_ + 4); \
    xzv[0] = *(const f32x4*)(xp_ + HID);      xzv[1] = *(const f32x4*)(xp_ + HID + 4); \
    xnv[0] = *(const f32x4*)(xp_ + 2 * HID);  xnv[1] = *(const f32x4*)(xp_ + 2 * HID + 4); \
  } while (0)

  // ---- publish h(0) into buffer 0, then entry barrier (gen 1) ----
  {
    union { u64 q[2]; f32x4 v4; } pk;
    pk.q[0] = packbf4(h[0], h[1], h[2], h[3]);
    pk.q[1] = packbf4(h[4], h[5], h[6], h[7]);
    uint64_t hw = (uint64_t)(hbf + hoff);
    asm volatile("global_store_dwordx4 %0, %1, off sc0 sc1" :: "v"(hw), "v"(pk.v4) : "memory");
    asm volatile("s_waitcnt vmcnt(0)" ::: "memory");
    __syncthreads();
    if (tid == 0)
      __hip_atomic_fetch_add(bar, 1u, __ATOMIC_RELAXED, __HIP_MEMORY_SCOPE_AGENT);
    LOAD_XW(0);
    if (tid == 0) {
      while (__hip_atomic_load(bar, __ATOMIC_RELAXED, __HIP_MEMORY_SCOPE_AGENT) < (unsigned)NB)
        __builtin_amdgcn_s_sleep(1);
    }
    __syncthreads();
  }

  for (int t = 0; t < T; ++t) {
    // clean vmcnt window: drain xw prefetch + spin loads before manual counting
    asm volatile("s_waitcnt vmcnt(0)" ::: "memory");

    const char* hbase = (const char*)hbf + (size_t)(t & 1) * (BATCH * (HID / 4) * 8);
    // lane reads batch row (nt*16+fr), bytes [km*1024 + ksl*64 + fk*16 .. +16)
    uint64_t ad0 = (uint64_t)(hbase + (size_t)(fr) * 2048 + km * 1024 + fk * 16);
    uint64_t ad1 = ad0 + 16 * 2048;
    uint64_t ad2 = ad0 + 32 * 2048;
    uint64_t ad3 = ad0 + 48 * 2048;

    f32x4 acc[3][4];
    #pragma unroll
    for (int mt = 0; mt < 3; ++mt)
      #pragma unroll
      for (int nt = 0; nt < 4; ++nt) acc[mt][nt] = (f32x4){};

    short8 bv[3][4];
    ISSUE(0, 0); ISSUE(1, 1); ISSUE(2, 2);
    KSTEPI(0, 0, 8);  KSTEPI(1, 1, 8);  KSTEPI(2, 2, 8);  KSTEPI(3, 0, 8);
    KSTEPI(4, 1, 8);  KSTEPI(5, 2, 8);  KSTEPI(6, 0, 8);  KSTEPI(7, 1, 8);
    KSTEPI(8, 2, 8);  KSTEPI(9, 0, 8);  KSTEPI(10, 1, 8); KSTEPI(11, 2, 8);
    KSTEPI(12, 0, 8); KSTEP(13, 1, 8);  KSTEP(14, 2, 4);  KSTEP(15, 0, 0);

    // cross-wave K reduce via LDS
    #pragma unroll
    for (int mt = 0; mt < 3; ++mt)
      #pragma unroll
      for (int nt = 0; nt < 4; ++nt)
        #pragma unroll
        for (int r = 0; r < 4; ++r)
          red[km][mm * 48 + mt * 16 + fk * 4 + r][nt * 16 + fr] = acc[mt][nt][r];
    __syncthreads();

    const int upd = (t < len_b);
    #pragma unroll
    for (int j = 0; j < 8; ++j) {
      const int u = j0 + j;
      float hrv = red[0][u][gb]      + red[1][u][gb]      + bb[0][u];
      float hzv = red[0][32 + u][gb] + red[1][32 + u][gb] + bb[1][u];
      float hnv = red[0][64 + u][gb] + red[1][64 + u][gb] + bb[2][u];
      float rr = sigm(xrv[j >> 2][j & 3] + hrv);
      float zz = sigm(xzv[j >> 2][j & 3] + hzv);
      float nn = tanh_fast(xnv[j >> 2][j & 3] + rr * hnv);
      float cc = (1.0f - zz) * nn + zz * h[j];
      h[j] = upd ? cc : h[j];
    }

    if (t + 1 < T) {
      union { u64 q[2]; f32x4 v4; } pk;
      pk.q[0] = packbf4(h[0], h[1], h[2], h[3]);
      pk.q[1] = packbf4(h[4], h[5], h[6], h[7]);
      uint64_t hw = (uint64_t)((char*)hbf + (size_t)((t + 1) & 1) * (BATCH * (HID / 4) * 8) + hoff * 8);
      asm volatile("global_store_dwordx4 %0, %1, off sc0 sc1" :: "v"(hw), "v"(pk.v4) : "memory");
      asm volatile("s_waitcnt vmcnt(0)" ::: "memory");   // h at coherent point
      __syncthreads();                                    // all waves' stores done
      if (tid == 0)
        __hip_atomic_fetch_add(bar, 1u, __ATOMIC_RELAXED, __HIP_MEMORY_SCOPE_AGENT);
      LOAD_XW(t + 1);   // prefetch next step's gate inputs under the barrier wait
      if (tid == 0) {
        const unsigned target = (unsigned)(t + 2) * (unsigned)NB;
        while (__hip_atomic_load(bar, __ATOMIC_RELAXED, __HIP_MEMORY_SCOPE_AGENT) < target)
          __builtin_amdgcn_s_sleep(1);
      }
      __syncthreads();
    }
  }

  #pragma unroll
  for (int j = 0; j < 8; ++j)
    hf32[(size_t)gb * HID + U0 + j0 + j] = h[j];
}

// ---------------- head: logits = tanh(h @ p1^T + b1) @ p2^T + b2 ----------------
__global__ __launch_bounds__(256) void head_kernel(
    const float* __restrict__ hf32, const float* __restrict__ p1W,
    const float* __restrict__ p1b, const float* __restrict__ p2W,
    const float* __restrict__ p2b, float* __restrict__ outp)
{
  int b = blockIdx.x;
  int tid = threadIdx.x;
  __shared__ float hrow[HID];
  __shared__ float red[4][64];
  __shared__ float s1[64];
  for (int d = tid; d < HID; d += 256) hrow[d] = hf32[(long)b * HID + d];
  __syncthreads();
  int j = tid & 63, q = tid >> 6;
  const float* wrow = p1W + (long)j * HID + q * 256;
  float s = 0.0f;
  for (int k = 0; k < 256; ++k) s += hrow[q * 256 + k] * wrow[k];
  red[q][j] = s;
  __syncthreads();
  if (tid < 64) {
    float v = red[0][tid] + red[1][tid] + red[2][tid] + red[3][tid] + p1b[tid];
    s1[tid] = tanh_fast(v);
  }
  __syncthreads();
  if (tid < 2) {
    float a = p2b[tid];
    for (int k = 0; k < 64; ++k) a += s1[k] * p2W[tid * 64 + k];
    outp[b * 2 + tid] = a;
  }
}

// ---------------- launch ----------------
extern "C" void kernel_launch(void* const* d_in, const int* in_sizes, int n_in,
                              void* d_out, int out_size, void* d_ws, size_t ws_size,
                              hipStream_t stream) {
  const int*   tgt_ids = (const int*)d_in[0];
  const int*   tgt_len = (const int*)d_in[1];
  const int*   src_ids = (const int*)d_in[2];
  const int*   src_len = (const int*)d_in[3];
  const float* emb  = (const float*)d_in[6];
  const float* sWih = (const float*)d_in[7];
  const float* sWhh = (const float*)d_in[8];
  const float* sbih = (const float*)d_in[9];
  const float* sbhh = (const float*)d_in[10];
  const float* tWih = (const float*)d_in[11];
  const float* tWhh = (const float*)d_in[12];
  const float* tbih = (const float*)d_in[13];
  const float* tbhh = (const float*)d_in[14];
  const float* p1W  = (const float*)d_in[19];
  const float* p1b  = (const float*)d_in[20];
  const float* p2W  = (const float*)d_in[21];
  const float* p2b  = (const float*)d_in[22];

  char* ws = (char*)d_ws;
  size_t off = 0;
  float* xw = (float*)(ws + off);                   off += (size_t)MROWS * G3 * 4;
  unsigned short* X  = (unsigned short*)(ws + off); off += (size_t)MROWS * DIM * 2;
  unsigned short* Wb = (unsigned short*)(ws + off); off += (size_t)G3 * DIM * 2;
  u64* hbf = (u64*)(ws + off);                      off += 2ull * BATCH * (HID / 4) * 8;
  float* hf32 = (float*)(ws + off);                 off += (size_t)BATCH * HID * 4;
  unsigned int* bars = (unsigned int*)(ws + off);   off += 256;
  if (ws_size < off) return;

  const int PREP_BLOCKS = MROWS + G3;  // 11264

  // src pipeline
  prep_kernel<<<PREP_BLOCKS, 256, 0, stream>>>(src_ids, emb, sWih, X, Wb, bars, 64);
  xw_gemm<<<dim3(G3 / BN, MROWS / BM), 256, 0, stream>>>(X, Wb, sbih, xw);
  gru_kernel<<<NB, 256, 0, stream>>>(sWhh, sbhh, xw, src_len, hbf, hf32, bars, TSEQ, 1);
  // tgt pipeline (h0 = src final hidden in hf32)
  prep_kernel<<<PREP_BLOCKS, 256, 0, stream>>>(tgt_ids, emb, tWih, X, Wb, nullptr, 0);
  xw_gemm<<<dim3(G3 / BN, MROWS / BM), 256, 0, stream>>>(X, Wb, tbih, xw);
  gru_kernel<<<NB, 256, 0, stream>>>(tWhh, tbhh, xw, tgt_len, hbf, hf32, bars + 32, TSEQ, 0);
  // head
  head_kernel<<<BATCH, 256, 0, stream>>>(hf32, p1W, p1b, p2W, p2b, (float*)d_out);
}

// Round 4
// 2517.799 us; speedup vs baseline: 2.3612x; 1.1772x over previous
//
#include <hip/hip_runtime.h>
#include <stdint.h>

typedef short short8 __attribute__((ext_vector_type(8)));
typedef float f32x4 __attribute__((ext_vector_type(4)));
typedef float f32x2 __attribute__((ext_vector_type(2)));
typedef unsigned long long u64;

#define TSEQ   128
#define BATCH  64
#define DIM    512
#define HID    1024
#define G3     3072
#define MROWS  (TSEQ * BATCH)   // 8192
#define NB     32               // gru grid (blocks)
#define HB     32               // hidden units per gru block

__device__ __forceinline__ unsigned short f2bf(float f) {
  union { float f; unsigned u; } v; v.f = f;
  unsigned u = v.u;
  return (unsigned short)((u + 0x7FFFu + ((u >> 16) & 1u)) >> 16);
}

__device__ __forceinline__ short8 pack8(f32x4 a, f32x4 b) {
  short8 r;
  r[0] = (short)f2bf(a.x); r[1] = (short)f2bf(a.y);
  r[2] = (short)f2bf(a.z); r[3] = (short)f2bf(a.w);
  r[4] = (short)f2bf(b.x); r[5] = (short)f2bf(b.y);
  r[6] = (short)f2bf(b.z); r[7] = (short)f2bf(b.w);
  return r;
}

__device__ __forceinline__ u64 packbf4(float a, float b, float c, float d) {
  return (u64)f2bf(a) | ((u64)f2bf(b) << 16) | ((u64)f2bf(c) << 32) | ((u64)f2bf(d) << 48);
}

__device__ __forceinline__ float sigm(float x) { return 1.0f / (1.0f + __expf(-x)); }
__device__ __forceinline__ float tanh_fast(float x) { return 2.0f / (1.0f + __expf(-2.0f * x)) - 1.0f; }

// ---------------- prep: gather emb rows + convert Wih to bf16 + zero barriers ----------------
__global__ __launch_bounds__(256) void prep_kernel(
    const int* __restrict__ ids, const float* __restrict__ emb,
    const float* __restrict__ wih, unsigned short* __restrict__ X,
    unsigned short* __restrict__ Wb, unsigned int* bars, int nbar)
{
  int row = blockIdx.x;
  int tid = threadIdx.x;
  const float* srcp;
  unsigned short* dst;
  if (row < MROWS) {
    srcp = emb + (long)ids[row] * DIM;
    dst  = X + (long)row * DIM;
  } else {
    int wr = row - MROWS;
    srcp = wih + (long)wr * DIM;
    dst  = Wb + (long)wr * DIM;
  }
  int d = tid * 2;
  f32x2 v = *(const f32x2*)(srcp + d);
  unsigned pk = (unsigned)f2bf(v.x) | ((unsigned)f2bf(v.y) << 16);
  *(unsigned*)(dst + d) = pk;
  if (bars != nullptr && row == 0 && tid < nbar) bars[tid] = 0u;
}

// ---------------- xW GEMM: C[m][n] = sum_k X[m][k]*W[n][k] + bih[n] ----------------
#define BM 128
#define BN 128
#define BK 32

__global__ __launch_bounds__(256) void xw_gemm(
    const unsigned short* __restrict__ X,   // [8192][512] bf16
    const unsigned short* __restrict__ W,   // [3072][512] bf16
    const float* __restrict__ bih,          // [3072]
    float* __restrict__ out)                // [8192][3072] f32
{
  __shared__ unsigned short As[BM * BK];
  __shared__ unsigned short Bs[BN * BK];
  int tid = threadIdx.x;
  int w = tid >> 6, l = tid & 63;
  int m0 = blockIdx.y * BM;
  int n0 = blockIdx.x * BN;
  int wr = w >> 1, wc = w & 1;

  int sr = tid >> 2, skq = tid & 3;
  int sr2 = sr + 64;
  int sgk  = (skq - (sr  >> 1)) & 3;
  int sgk2 = (skq - (sr2 >> 1)) & 3;
  const unsigned short* gA0 = X + (long)(m0 + sr ) * DIM + sgk  * 8;
  const unsigned short* gA1 = X + (long)(m0 + sr2) * DIM + sgk2 * 8;
  const unsigned short* gB0 = W + (long)(n0 + sr ) * DIM + sgk  * 8;
  const unsigned short* gB1 = W + (long)(n0 + sr2) * DIM + sgk2 * 8;
  unsigned short* lA0 = As + sr  * BK + skq * 8;
  unsigned short* lA1 = As + sr2 * BK + skq * 8;
  unsigned short* lB0 = Bs + sr  * BK + skq * 8;
  unsigned short* lB1 = Bs + sr2 * BK + skq * 8;

  f32x4 acc[4][4];
  #pragma unroll
  for (int mt = 0; mt < 4; ++mt)
    #pragma unroll
    for (int nt = 0; nt < 4; ++nt) acc[mt][nt] = (f32x4){};

  short8 va0 = *(const short8*)(gA0);
  short8 va1 = *(const short8*)(gA1);
  short8 vb0 = *(const short8*)(gB0);
  short8 vb1 = *(const short8*)(gB1);

  int fr = l & 15, fk = l >> 4;
  for (int kt = 0; kt < DIM / BK; ++kt) {
    __syncthreads();
    *(short8*)lA0 = va0; *(short8*)lA1 = va1;
    *(short8*)lB0 = vb0; *(short8*)lB1 = vb1;
    __syncthreads();
    if (kt + 1 < DIM / BK) {
      int ko = (kt + 1) * BK;
      va0 = *(const short8*)(gA0 + ko);
      va1 = *(const short8*)(gA1 + ko);
      vb0 = *(const short8*)(gB0 + ko);
      vb1 = *(const short8*)(gB1 + ko);
    }
    short8 af[4], bf[4];
    #pragma unroll
    for (int mt = 0; mt < 4; ++mt) {
      int r = wr * 64 + mt * 16 + fr;
      int slot = ((r >> 1) + fk) & 3;
      af[mt] = *(const short8*)(As + r * BK + slot * 8);
    }
    #pragma unroll
    for (int nt = 0; nt < 4; ++nt) {
      int r = wc * 64 + nt * 16 + fr;
      int slot = ((r >> 1) + fk) & 3;
      bf[nt] = *(const short8*)(Bs + r * BK + slot * 8);
    }
    #pragma unroll
    for (int mt = 0; mt < 4; ++mt)
      #pragma unroll
      for (int nt = 0; nt < 4; ++nt)
        acc[mt][nt] = __builtin_amdgcn_mfma_f32_16x16x32_bf16(af[mt], bf[nt], acc[mt][nt], 0, 0, 0);
  }

  #pragma unroll
  for (int nt = 0; nt < 4; ++nt) {
    int n = n0 + wc * 64 + nt * 16 + fr;
    float bias = bih[n];
    #pragma unroll
    for (int mt = 0; mt < 4; ++mt) {
      int mbase = m0 + wr * 64 + mt * 16 + fk * 4;
      #pragma unroll
      for (int r = 0; r < 4; ++r)
        out[(long)(mbase + r) * G3 + n] = acc[mt][nt][r] + bias;
    }
  }
}

// ---------------- persistent masked GRU ----------------
// Protocol identical to the passing R2/R3 kernels (sc0sc1 h exchange through IF,
// direct counter-spin barrier). Mechanics changed:
//  - wave = K-QUARTER (no duplicate B reads: 128 KB/block/step, was 256 KB)
//  - 24 loads in flight, monotone counted vmcnt (max MLP)
//  - 4 K-partials -> two-stage LDS reduce (waves 0,1 write; 2,3 add)
#define MF(a, b, c) __builtin_amdgcn_mfma_f32_16x16x32_bf16(a, b, c, 0, 0, 0)

#define ISSUE(ss, kk) do { \
  asm volatile("global_load_dwordx4 %0, %1, off offset:%2 sc0 sc1" \
               : "=v"(bv[ss][0]) : "v"(ad0), "i"((kk) * 64) : "memory"); \
  asm volatile("global_load_dwordx4 %0, %1, off offset:%2 sc0 sc1" \
               : "=v"(bv[ss][1]) : "v"(ad1), "i"((kk) * 64) : "memory"); \
  asm volatile("global_load_dwordx4 %0, %1, off offset:%2 sc0 sc1" \
               : "=v"(bv[ss][2]) : "v"(ad2), "i"((kk) * 64) : "memory"); \
  asm volatile("global_load_dwordx4 %0, %1, off offset:%2 sc0 sc1" \
               : "=v"(bv[ss][3]) : "v"(ad3), "i"((kk) * 64) : "memory"); \
} while (0)

#define MF6(kk, ss, nt) \
  acc[0][nt] = MF(areg[0][kk], bv[ss][nt], acc[0][nt]); \
  acc[1][nt] = MF(areg[1][kk], bv[ss][nt], acc[1][nt]); \
  acc[2][nt] = MF(areg[2][kk], bv[ss][nt], acc[2][nt]); \
  acc[3][nt] = MF(areg[3][kk], bv[ss][nt], acc[3][nt]); \
  acc[4][nt] = MF(areg[4][kk], bv[ss][nt], acc[4][nt]); \
  acc[5][nt] = MF(areg[5][kk], bv[ss][nt], acc[5][nt]);

#define CONS(kk, ss, wn) do { \
  asm volatile("s_waitcnt vmcnt(" #wn ")" ::: "memory"); \
  __builtin_amdgcn_sched_barrier(0); \
  MF6(kk, ss, 0) MF6(kk, ss, 1) MF6(kk, ss, 2) MF6(kk, ss, 3) \
} while (0)

#define CONSI(kk, ss, wn, nk) do { CONS(kk, ss, wn); ISSUE(ss, nk); } while (0)

__global__ __launch_bounds__(256, 1) void gru_kernel(
    const float* __restrict__ Whh, const float* __restrict__ bhh,
    const float* __restrict__ xw, const int* __restrict__ lengths,
    u64* __restrict__ hbf,            // [2][BATCH][HID/4] u64 (4 bf16 each)
    float* __restrict__ hf32,         // [BATCH][HID]
    unsigned int* __restrict__ bar, int T, int initzero)
{
  const int tid = threadIdx.x;
  const int w = tid >> 6, l = tid & 63;
  const int fr = l & 15, fk = l >> 4;
  const int U0 = blockIdx.x * HB;

  // ---- Whh fragments -> registers: wave w holds ALL 96 gate rows, K-quarter w*256..+255 ----
  short8 areg[6][8];
  #pragma unroll
  for (int mt = 0; mt < 6; ++mt) {
    const int m = mt * 16 + fr;                    // 0..95
    const int gate = m >> 5, u = m & 31;
    const float* wp = Whh + (size_t)(gate * HID + U0 + u) * HID + w * 256 + fk * 8;
    #pragma unroll
    for (int ksl = 0; ksl < 8; ++ksl) {
      f32x4 a0 = *(const f32x4*)(wp + ksl * 32);
      f32x4 a1 = *(const f32x4*)(wp + ksl * 32 + 4);
      areg[mt][ksl] = pack8(a0, a1);
    }
  }

  // ---- gate-phase ownership: batch gb = lane, units j0..j0+7 (j0 = wave*8) ----
  const int gb = l;
  const int j0 = w * 8;
  const size_t hoff = (size_t)gb * (HID / 4) + (size_t)(U0 + j0) / 4;  // u64 units
  const int len_b = lengths[gb];

  float h[8];
  #pragma unroll
  for (int j = 0; j < 8; ++j)
    h[j] = initzero ? 0.0f : hf32[(size_t)gb * HID + U0 + j0 + j];

  __shared__ float red[2][96][67];   // 51 KB; [kpair][gate-row][batch]
  __shared__ float bb[3][32];        // biases for this block's 32 units x 3 gates
  if (tid < 96) bb[tid >> 5][tid & 31] = bhh[(tid >> 5) * HID + U0 + (tid & 31)];

  f32x4 xrv[2], xzv[2], xnv[2];
  #define LOAD_XW(tt) do { \
    const float* xp_ = xw + ((size_t)(tt) * BATCH + gb) * G3 + U0 + j0; \
    xrv[0] = *(const f32x4*)(xp_);            xrv[1] = *(const f32x4*)(xp_ + 4); \
    xzv[0] = *(const f32x4*)(xp_ + HID);      xzv[1] = *(const f32x4*)(xp_ + HID + 4); \
    xnv[0] = *(const f32x4*)(xp_ + 2 * HID);  xnv[1] = *(const f32x4*)(xp_ + 2 * HID + 4); \
  } while (0)

  // ---- publish h(0) into buffer 0, then entry barrier (gen 1) ----
  {
    union { u64 q[2]; f32x4 v4; } pk;
    pk.q[0] = packbf4(h[0], h[1], h[2], h[3]);
    pk.q[1] = packbf4(h[4], h[5], h[6], h[7]);
    uint64_t hw = (uint64_t)(hbf + hoff);
    asm volatile("global_store_dwordx4 %0, %1, off sc0 sc1" :: "v"(hw), "v"(pk.v4) : "memory");
    asm volatile("s_waitcnt vmcnt(0)" ::: "memory");
    __syncthreads();
    if (tid == 0)
      __hip_atomic_fetch_add(bar, 1u, __ATOMIC_RELAXED, __HIP_MEMORY_SCOPE_AGENT);
    LOAD_XW(0);
    if (tid == 0) {
      while (__hip_atomic_load(bar, __ATOMIC_RELAXED, __HIP_MEMORY_SCOPE_AGENT) < (unsigned)NB)
        __builtin_amdgcn_s_sleep(1);
    }
    __syncthreads();
  }

  for (int t = 0; t < T; ++t) {
    // clean vmcnt window: drain xw prefetch + spin loads before manual counting
    asm volatile("s_waitcnt vmcnt(0)" ::: "memory");

    const char* hbase = (const char*)hbf + (size_t)(t & 1) * (BATCH * (HID / 4) * 8);
    // lane reads batch row (nt*16+fr), bytes [w*512 + ksl*64 + fk*16 .. +16)
    uint64_t ad0 = (uint64_t)(hbase + (size_t)(fr) * 2048 + w * 512 + fk * 16);
    uint64_t ad1 = ad0 + 16 * 2048;
    uint64_t ad2 = ad0 + 32 * 2048;
    uint64_t ad3 = ad0 + 48 * 2048;

    f32x4 acc[6][4];
    #pragma unroll
    for (int mt = 0; mt < 6; ++mt)
      #pragma unroll
      for (int nt = 0; nt < 4; ++nt) acc[mt][nt] = (f32x4){};

    short8 bv[6][4];
    ISSUE(0, 0); ISSUE(1, 1); ISSUE(2, 2); ISSUE(3, 3); ISSUE(4, 4); ISSUE(5, 5);
    CONSI(0, 0, 20, 6);
    CONSI(1, 1, 20, 7);
    CONS(2, 2, 20);
    CONS(3, 3, 16);
    CONS(4, 4, 12);
    CONS(5, 5, 8);
    CONS(6, 0, 4);
    CONS(7, 1, 0);

    // two-stage cross-wave K reduce via LDS (4 quarters -> 2 pairs -> sum)
    if (w < 2) {
      #pragma unroll
      for (int mt = 0; mt < 6; ++mt)
        #pragma unroll
        for (int nt = 0; nt < 4; ++nt)
          #pragma unroll
          for (int r = 0; r < 4; ++r)
            red[w][mt * 16 + fk * 4 + r][nt * 16 + fr] = acc[mt][nt][r];
    }
    __syncthreads();
    if (w >= 2) {
      #pragma unroll
      for (int mt = 0; mt < 6; ++mt)
        #pragma unroll
        for (int nt = 0; nt < 4; ++nt)
          #pragma unroll
          for (int r = 0; r < 4; ++r)
            red[w - 2][mt * 16 + fk * 4 + r][nt * 16 + fr] += acc[mt][nt][r];
    }
    __syncthreads();

    const int upd = (t < len_b);
    #pragma unroll
    for (int j = 0; j < 8; ++j) {
      const int u = j0 + j;
      float hrv = red[0][u][gb]      + red[1][u][gb]      + bb[0][u];
      float hzv = red[0][32 + u][gb] + red[1][32 + u][gb] + bb[1][u];
      float hnv = red[0][64 + u][gb] + red[1][64 + u][gb] + bb[2][u];
      float rr = sigm(xrv[j >> 2][j & 3] + hrv);
      float zz = sigm(xzv[j >> 2][j & 3] + hzv);
      float nn = tanh_fast(xnv[j >> 2][j & 3] + rr * hnv);
      float cc = (1.0f - zz) * nn + zz * h[j];
      h[j] = upd ? cc : h[j];
    }

    if (t + 1 < T) {
      union { u64 q[2]; f32x4 v4; } pk;
      pk.q[0] = packbf4(h[0], h[1], h[2], h[3]);
      pk.q[1] = packbf4(h[4], h[5], h[6], h[7]);
      uint64_t hw = (uint64_t)((char*)hbf + (size_t)((t + 1) & 1) * (BATCH * (HID / 4) * 8) + hoff * 8);
      asm volatile("global_store_dwordx4 %0, %1, off sc0 sc1" :: "v"(hw), "v"(pk.v4) : "memory");
      asm volatile("s_waitcnt vmcnt(0)" ::: "memory");   // h at coherent point
      __syncthreads();                                    // all waves' stores done
      if (tid == 0)
        __hip_atomic_fetch_add(bar, 1u, __ATOMIC_RELAXED, __HIP_MEMORY_SCOPE_AGENT);
      LOAD_XW(t + 1);   // prefetch next step's gate inputs under the barrier wait
      if (tid == 0) {
        const unsigned target = (unsigned)(t + 2) * (unsigned)NB;
        while (__hip_atomic_load(bar, __ATOMIC_RELAXED, __HIP_MEMORY_SCOPE_AGENT) < target)
          __builtin_amdgcn_s_sleep(1);
      }
      __syncthreads();
    }
  }

  #pragma unroll
  for (int j = 0; j < 8; ++j)
    hf32[(size_t)gb * HID + U0 + j0 + j] = h[j];
}

// ---------------- head: logits = tanh(h @ p1^T + b1) @ p2^T + b2 ----------------
__global__ __launch_bounds__(256) void head_kernel(
    const float* __restrict__ hf32, const float* __restrict__ p1W,
    const float* __restrict__ p1b, const float* __restrict__ p2W,
    const float* __restrict__ p2b, float* __restrict__ outp)
{
  int b = blockIdx.x;
  int tid = threadIdx.x;
  __shared__ float hrow[HID];
  __shared__ float red[4][64];
  __shared__ float s1[64];
  for (int d = tid; d < HID; d += 256) hrow[d] = hf32[(long)b * HID + d];
  __syncthreads();
  int j = tid & 63, q = tid >> 6;
  const float* wrow = p1W + (long)j * HID + q * 256;
  float s = 0.0f;
  for (int k = 0; k < 256; ++k) s += hrow[q * 256 + k] * wrow[k];
  red[q][j] = s;
  __syncthreads();
  if (tid < 64) {
    float v = red[0][tid] + red[1][tid] + red[2][tid] + red[3][tid] + p1b[tid];
    s1[tid] = tanh_fast(v);
  }
  __syncthreads();
  if (tid < 2) {
    float a = p2b[tid];
    for (int k = 0; k < 64; ++k) a += s1[k] * p2W[tid * 64 + k];
    outp[b * 2 + tid] = a;
  }
}

// ---------------- launch ----------------
extern "C" void kernel_launch(void* const* d_in, const int* in_sizes, int n_in,
                              void* d_out, int out_size, void* d_ws, size_t ws_size,
                              hipStream_t stream) {
  const int*   tgt_ids = (const int*)d_in[0];
  const int*   tgt_len = (const int*)d_in[1];
  const int*   src_ids = (const int*)d_in[2];
  const int*   src_len = (const int*)d_in[3];
  const float* emb  = (const float*)d_in[6];
  const float* sWih = (const float*)d_in[7];
  const float* sWhh = (const float*)d_in[8];
  const float* sbih = (const float*)d_in[9];
  const float* sbhh = (const float*)d_in[10];
  const float* tWih = (const float*)d_in[11];
  const float* tWhh = (const float*)d_in[12];
  const float* tbih = (const float*)d_in[13];
  const float* tbhh = (const float*)d_in[14];
  const float* p1W  = (const float*)d_in[19];
  const float* p1b  = (const float*)d_in[20];
  const float* p2W  = (const float*)d_in[21];
  const float* p2b  = (const float*)d_in[22];

  char* ws = (char*)d_ws;
  size_t off = 0;
  float* xw = (float*)(ws + off);                   off += (size_t)MROWS * G3 * 4;
  unsigned short* X  = (unsigned short*)(ws + off); off += (size_t)MROWS * DIM * 2;
  unsigned short* Wb = (unsigned short*)(ws + off); off += (size_t)G3 * DIM * 2;
  u64* hbf = (u64*)(ws + off);                      off += 2ull * BATCH * (HID / 4) * 8;
  float* hf32 = (float*)(ws + off);                 off += (size_t)BATCH * HID * 4;
  unsigned int* bars = (unsigned int*)(ws + off);   off += 256;
  if (ws_size < off) return;

  const int PREP_BLOCKS = MROWS + G3;  // 11264

  // src pipeline
  prep_kernel<<<PREP_BLOCKS, 256, 0, stream>>>(src_ids, emb, sWih, X, Wb, bars, 64);
  xw_gemm<<<dim3(G3 / BN, MROWS / BM), 256, 0, stream>>>(X, Wb, sbih, xw);
  gru_kernel<<<NB, 256, 0, stream>>>(sWhh, sbhh, xw, src_len, hbf, hf32, bars, TSEQ, 1);
  // tgt pipeline (h0 = src final hidden in hf32)
  prep_kernel<<<PREP_BLOCKS, 256, 0, stream>>>(tgt_ids, emb, tWih, X, Wb, nullptr, 0);
  xw_gemm<<<dim3(G3 / BN, MROWS / BM), 256, 0, stream>>>(X, Wb, tbih, xw);
  gru_kernel<<<NB, 256, 0, stream>>>(tWhh, tbhh, xw, tgt_len, hbf, hf32, bars + 32, TSEQ, 0);
  // head
  head_kernel<<<BATCH, 256, 0, stream>>>(hf32, p1W, p1b, p2W, p2b, (float*)d_out);
}

// Round 5
// 2315.798 us; speedup vs baseline: 2.5672x; 1.0872x over previous
//
#include <hip/hip_runtime.h>
#include <stdint.h>

typedef short short8 __attribute__((ext_vector_type(8)));
typedef float f32x4 __attribute__((ext_vector_type(4)));
typedef float f32x2 __attribute__((ext_vector_type(2)));
typedef unsigned long long u64;

#define TSEQ   128
#define BATCH  64
#define DIM    512
#define HID    1024
#define G3     3072
#define MROWS  (TSEQ * BATCH)   // 8192
#define NB     32               // gru grid (blocks)
#define HB     32               // hidden units per gru block

__device__ __forceinline__ unsigned short f2bf(float f) {
  union { float f; unsigned u; } v; v.f = f;
  unsigned u = v.u;
  return (unsigned short)((u + 0x7FFFu + ((u >> 16) & 1u)) >> 16);
}

__device__ __forceinline__ short8 pack8(f32x4 a, f32x4 b) {
  short8 r;
  r[0] = (short)f2bf(a.x); r[1] = (short)f2bf(a.y);
  r[2] = (short)f2bf(a.z); r[3] = (short)f2bf(a.w);
  r[4] = (short)f2bf(b.x); r[5] = (short)f2bf(b.y);
  r[6] = (short)f2bf(b.z); r[7] = (short)f2bf(b.w);
  return r;
}

__device__ __forceinline__ u64 packbf4(float a, float b, float c, float d) {
  return (u64)f2bf(a) | ((u64)f2bf(b) << 16) | ((u64)f2bf(c) << 32) | ((u64)f2bf(d) << 48);
}

__device__ __forceinline__ float sigm(float x) { return 1.0f / (1.0f + __expf(-x)); }
__device__ __forceinline__ float tanh_fast(float x) { return 2.0f / (1.0f + __expf(-2.0f * x)) - 1.0f; }

// ---------------- prep: gather emb rows + convert Wih to bf16 + zero flags ----------------
__global__ __launch_bounds__(256) void prep_kernel(
    const int* __restrict__ ids, const float* __restrict__ emb,
    const float* __restrict__ wih, unsigned short* __restrict__ X,
    unsigned short* __restrict__ Wb, unsigned int* bars)
{
  int row = blockIdx.x;
  int tid = threadIdx.x;
  const float* srcp;
  unsigned short* dst;
  if (row < MROWS) {
    srcp = emb + (long)ids[row] * DIM;
    dst  = X + (long)row * DIM;
  } else {
    int wr = row - MROWS;
    srcp = wih + (long)wr * DIM;
    dst  = Wb + (long)wr * DIM;
  }
  int d = tid * 2;
  f32x2 v = *(const f32x2*)(srcp + d);
  unsigned pk = (unsigned)f2bf(v.x) | ((unsigned)f2bf(v.y) << 16);
  *(unsigned*)(dst + d) = pk;
  if (bars != nullptr && row == 0) ((f32x4*)bars)[tid] = (f32x4){};  // zero 4 KB of flags
}

// ---------------- xW GEMM: C[m][n] = sum_k X[m][k]*W[n][k] + bih[n] ----------------
#define BM 128
#define BN 128
#define BK 32

__global__ __launch_bounds__(256) void xw_gemm(
    const unsigned short* __restrict__ X,   // [8192][512] bf16
    const unsigned short* __restrict__ W,   // [3072][512] bf16
    const float* __restrict__ bih,          // [3072]
    float* __restrict__ out)                // [8192][3072] f32
{
  __shared__ unsigned short As[BM * BK];
  __shared__ unsigned short Bs[BN * BK];
  int tid = threadIdx.x;
  int w = tid >> 6, l = tid & 63;
  int m0 = blockIdx.y * BM;
  int n0 = blockIdx.x * BN;
  int wr = w >> 1, wc = w & 1;

  int sr = tid >> 2, skq = tid & 3;
  int sr2 = sr + 64;
  int sgk  = (skq - (sr  >> 1)) & 3;
  int sgk2 = (skq - (sr2 >> 1)) & 3;
  const unsigned short* gA0 = X + (long)(m0 + sr ) * DIM + sgk  * 8;
  const unsigned short* gA1 = X + (long)(m0 + sr2) * DIM + sgk2 * 8;
  const unsigned short* gB0 = W + (long)(n0 + sr ) * DIM + sgk  * 8;
  const unsigned short* gB1 = W + (long)(n0 + sr2) * DIM + sgk2 * 8;
  unsigned short* lA0 = As + sr  * BK + skq * 8;
  unsigned short* lA1 = As + sr2 * BK + skq * 8;
  unsigned short* lB0 = Bs + sr  * BK + skq * 8;
  unsigned short* lB1 = Bs + sr2 * BK + skq * 8;

  f32x4 acc[4][4];
  #pragma unroll
  for (int mt = 0; mt < 4; ++mt)
    #pragma unroll
    for (int nt = 0; nt < 4; ++nt) acc[mt][nt] = (f32x4){};

  short8 va0 = *(const short8*)(gA0);
  short8 va1 = *(const short8*)(gA1);
  short8 vb0 = *(const short8*)(gB0);
  short8 vb1 = *(const short8*)(gB1);

  int fr = l & 15, fk = l >> 4;
  for (int kt = 0; kt < DIM / BK; ++kt) {
    __syncthreads();
    *(short8*)lA0 = va0; *(short8*)lA1 = va1;
    *(short8*)lB0 = vb0; *(short8*)lB1 = vb1;
    __syncthreads();
    if (kt + 1 < DIM / BK) {
      int ko = (kt + 1) * BK;
      va0 = *(const short8*)(gA0 + ko);
      va1 = *(const short8*)(gA1 + ko);
      vb0 = *(const short8*)(gB0 + ko);
      vb1 = *(const short8*)(gB1 + ko);
    }
    short8 af[4], bf[4];
    #pragma unroll
    for (int mt = 0; mt < 4; ++mt) {
      int r = wr * 64 + mt * 16 + fr;
      int slot = ((r >> 1) + fk) & 3;
      af[mt] = *(const short8*)(As + r * BK + slot * 8);
    }
    #pragma unroll
    for (int nt = 0; nt < 4; ++nt) {
      int r = wc * 64 + nt * 16 + fr;
      int slot = ((r >> 1) + fk) & 3;
      bf[nt] = *(const short8*)(Bs + r * BK + slot * 8);
    }
    #pragma unroll
    for (int mt = 0; mt < 4; ++mt)
      #pragma unroll
      for (int nt = 0; nt < 4; ++nt)
        acc[mt][nt] = __builtin_amdgcn_mfma_f32_16x16x32_bf16(af[mt], bf[nt], acc[mt][nt], 0, 0, 0);
  }

  #pragma unroll
  for (int nt = 0; nt < 4; ++nt) {
    int n = n0 + wc * 64 + nt * 16 + fr;
    float bias = bih[n];
    #pragma unroll
    for (int mt = 0; mt < 4; ++mt) {
      int mbase = m0 + wr * 64 + mt * 16 + fk * 4;
      #pragma unroll
      for (int r = 0; r < 4; ++r)
        out[(long)(mbase + r) * G3 + n] = acc[mt][nt][r] + bias;
    }
  }
}

// ---------------- persistent masked GRU ----------------
// Dataflow as R4 (wave = K-quarter, A in regs, 24-deep pipelined B loads).
// Coherence mechanics changed:
//  - h stores sc0sc1 (through to IF); h LOADS are sc0-only (L2-cacheable),
//    made safe by a per-step `buffer_inv sc1` (agent-acquire half) after the
//    barrier -> the 4 blocks/XCD share one IF fetch, rest are L2 hits.
//  - RMW-free barrier: per-block flag stores (64B-strided), wave0 lanes poll
//    all 32 flags with one vector load + __any.
//  - reduce: 4 write-only slices, ds_write_b128/ds_read_b128, no RMW stage.
#define MF(a, b, c) __builtin_amdgcn_mfma_f32_16x16x32_bf16(a, b, c, 0, 0, 0)

#define ISSUE(ss, kk) do { \
  asm volatile("global_load_dwordx4 %0, %1, off offset:%2 sc0" \
               : "=v"(bv[ss][0]) : "v"(ad0), "i"((kk) * 64) : "memory"); \
  asm volatile("global_load_dwordx4 %0, %1, off offset:%2 sc0" \
               : "=v"(bv[ss][1]) : "v"(ad1), "i"((kk) * 64) : "memory"); \
  asm volatile("global_load_dwordx4 %0, %1, off offset:%2 sc0" \
               : "=v"(bv[ss][2]) : "v"(ad2), "i"((kk) * 64) : "memory"); \
  asm volatile("global_load_dwordx4 %0, %1, off offset:%2 sc0" \
               : "=v"(bv[ss][3]) : "v"(ad3), "i"((kk) * 64) : "memory"); \
} while (0)

#define MF6(kk, ss, nt) \
  acc[0][nt] = MF(areg[0][kk], bv[ss][nt], acc[0][nt]); \
  acc[1][nt] = MF(areg[1][kk], bv[ss][nt], acc[1][nt]); \
  acc[2][nt] = MF(areg[2][kk], bv[ss][nt], acc[2][nt]); \
  acc[3][nt] = MF(areg[3][kk], bv[ss][nt], acc[3][nt]); \
  acc[4][nt] = MF(areg[4][kk], bv[ss][nt], acc[4][nt]); \
  acc[5][nt] = MF(areg[5][kk], bv[ss][nt], acc[5][nt]);

#define CONS(kk, ss, wn) do { \
  asm volatile("s_waitcnt vmcnt(" #wn ")" ::: "memory"); \
  __builtin_amdgcn_sched_barrier(0); \
  MF6(kk, ss, 0) MF6(kk, ss, 1) MF6(kk, ss, 2) MF6(kk, ss, 3) \
} while (0)

#define CONSI(kk, ss, wn, nk) do { CONS(kk, ss, wn); ISSUE(ss, nk); } while (0)

// arrive: h stores already issued; drain, block-sync, publish generation flag
#define BARRIER_ARRIVE(tgtv) do { \
  asm volatile("s_waitcnt vmcnt(0)" ::: "memory"); \
  __syncthreads(); \
  if (tid == 0) { \
    unsigned fv_ = (unsigned)(tgtv); \
    uint64_t fa_ = (uint64_t)(bar + (blockIdx.x << 4)); \
    asm volatile("global_store_dword %0, %1, off sc0 sc1" :: "v"(fa_), "v"(fv_) : "memory"); \
  } \
} while (0)

// wait: lanes 0..31 of wave0 poll all flags; then agent-acquire (L2 inv)
#define BARRIER_WAIT(tgtv) do { \
  if (tid < NB) { \
    unsigned v_; \
    uint64_t pa_ = (uint64_t)(bar + (tid << 4)); \
    do { \
      asm volatile("global_load_dword %0, %1, off sc0 sc1" : "=v"(v_) : "v"(pa_) : "memory"); \
      asm volatile("s_waitcnt vmcnt(0)" ::: "memory"); \
    } while (__any(v_ < (unsigned)(tgtv))); \
  } \
  __syncthreads(); \
  asm volatile("buffer_inv sc1" ::: "memory"); \
} while (0)

__global__ __launch_bounds__(256, 1) void gru_kernel(
    const float* __restrict__ Whh, const float* __restrict__ bhh,
    const float* __restrict__ xw, const int* __restrict__ lengths,
    u64* __restrict__ hbf,            // [2][BATCH][HID/4] u64 (4 bf16 each)
    float* __restrict__ hf32,         // [BATCH][HID]
    unsigned int* __restrict__ bar, int T, int initzero)
{
  const int tid = threadIdx.x;
  const int w = tid >> 6, l = tid & 63;
  const int fr = l & 15, fk = l >> 4;
  const int U0 = blockIdx.x * HB;

  // ---- Whh fragments -> registers: wave w holds ALL 96 gate rows, K-quarter w*256..+255 ----
  short8 areg[6][8];
  #pragma unroll
  for (int mt = 0; mt < 6; ++mt) {
    const int m = mt * 16 + fr;                    // 0..95
    const int gate = m >> 5, u = m & 31;
    const float* wp = Whh + (size_t)(gate * HID + U0 + u) * HID + w * 256 + fk * 8;
    #pragma unroll
    for (int ksl = 0; ksl < 8; ++ksl) {
      f32x4 a0 = *(const f32x4*)(wp + ksl * 32);
      f32x4 a1 = *(const f32x4*)(wp + ksl * 32 + 4);
      areg[mt][ksl] = pack8(a0, a1);
    }
  }

  // ---- gate-phase ownership: batch gb = lane, units j0..j0+7 (j0 = wave*8) ----
  const int gb = l;
  const int j0 = w * 8;
  const size_t hoff = (size_t)gb * (HID / 4) + (size_t)(U0 + j0) / 4;  // u64 units
  const int len_b = lengths[gb];

  float h[8];
  #pragma unroll
  for (int j = 0; j < 8; ++j)
    h[j] = initzero ? 0.0f : hf32[(size_t)gb * HID + U0 + j0 + j];

  __shared__ float red2[4][64][100];   // 102.4 KB; [k-slice][batch][gate-row(+pad)]
  __shared__ float bb[3][32];          // biases for this block's 32 units x 3 gates
  if (tid < 96) bb[tid >> 5][tid & 31] = bhh[(tid >> 5) * HID + U0 + (tid & 31)];

  f32x4 xrv[2], xzv[2], xnv[2];
  #define LOAD_XW(tt) do { \
    const float* xp_ = xw + ((size_t)(tt) * BATCH + gb) * G3 + U0 + j0; \
    xrv[0] = *(const f32x4*)(xp_);            xrv[1] = *(const f32x4*)(xp_ + 4); \
    xzv[0] = *(const f32x4*)(xp_ + HID);      xzv[1] = *(const f32x4*)(xp_ + HID + 4); \
    xnv[0] = *(const f32x4*)(xp_ + 2 * HID);  xnv[1] = *(const f32x4*)(xp_ + 2 * HID + 4); \
  } while (0)

  // ---- publish h(0) into buffer 0, then entry barrier (gen 1) ----
  {
    union { u64 q[2]; f32x4 v4; } pk;
    pk.q[0] = packbf4(h[0], h[1], h[2], h[3]);
    pk.q[1] = packbf4(h[4], h[5], h[6], h[7]);
    uint64_t hw = (uint64_t)(hbf + hoff);
    asm volatile("global_store_dwordx4 %0, %1, off sc0 sc1" :: "v"(hw), "v"(pk.v4) : "memory");
    BARRIER_ARRIVE(1);
    LOAD_XW(0);
    BARRIER_WAIT(1);
  }

  for (int t = 0; t < T; ++t) {
    // drain xw prefetch / spin loads / buffer_inv before manual vmcnt counting
    asm volatile("s_waitcnt vmcnt(0)" ::: "memory");

    const char* hbase = (const char*)hbf + (size_t)(t & 1) * (BATCH * (HID / 4) * 8);
    // lane reads batch row (nt*16+fr), bytes [w*512 + ksl*64 + fk*16 .. +16)
    uint64_t ad0 = (uint64_t)(hbase + (size_t)(fr) * 2048 + w * 512 + fk * 16);
    uint64_t ad1 = ad0 + 16 * 2048;
    uint64_t ad2 = ad0 + 32 * 2048;
    uint64_t ad3 = ad0 + 48 * 2048;

    f32x4 acc[6][4];
    #pragma unroll
    for (int mt = 0; mt < 6; ++mt)
      #pragma unroll
      for (int nt = 0; nt < 4; ++nt) acc[mt][nt] = (f32x4){};

    short8 bv[6][4];
    ISSUE(0, 0); ISSUE(1, 1); ISSUE(2, 2); ISSUE(3, 3); ISSUE(4, 4); ISSUE(5, 5);
    CONSI(0, 0, 20, 6);
    CONSI(1, 1, 20, 7);
    CONS(2, 2, 20);
    CONS(3, 3, 16);
    CONS(4, 4, 12);
    CONS(5, 5, 8);
    CONS(6, 0, 4);
    CONS(7, 1, 0);

    // per-wave K-slice -> LDS, write-only, vectorized
    #pragma unroll
    for (int mt = 0; mt < 6; ++mt)
      #pragma unroll
      for (int nt = 0; nt < 4; ++nt)
        *(f32x4*)&red2[w][nt * 16 + fr][mt * 16 + fk * 4] = acc[mt][nt];
    __syncthreads();

    // gates: sum 4 K-slices (vector LDS reads), add bias, update h
    #define RD4(s, row) (*(const f32x4*)&red2[s][gb][row])
    f32x4 sr_[2], sz_[2], sn_[2];
    #pragma unroll
    for (int hh = 0; hh < 2; ++hh) {
      const int rbase = j0 + hh * 4;
      sr_[hh] = RD4(0, rbase)      + RD4(1, rbase)      + RD4(2, rbase)      + RD4(3, rbase)      + *(const f32x4*)&bb[0][rbase];
      sz_[hh] = RD4(0, 32 + rbase) + RD4(1, 32 + rbase) + RD4(2, 32 + rbase) + RD4(3, 32 + rbase) + *(const f32x4*)&bb[1][rbase];
      sn_[hh] = RD4(0, 64 + rbase) + RD4(1, 64 + rbase) + RD4(2, 64 + rbase) + RD4(3, 64 + rbase) + *(const f32x4*)&bb[2][rbase];
    }

    const int upd = (t < len_b);
    #pragma unroll
    for (int j = 0; j < 8; ++j) {
      float rr = sigm(xrv[j >> 2][j & 3] + sr_[j >> 2][j & 3]);
      float zz = sigm(xzv[j >> 2][j & 3] + sz_[j >> 2][j & 3]);
      float nn = tanh_fast(xnv[j >> 2][j & 3] + rr * sn_[j >> 2][j & 3]);
      float cc = (1.0f - zz) * nn + zz * h[j];
      h[j] = upd ? cc : h[j];
    }

    if (t + 1 < T) {
      union { u64 q[2]; f32x4 v4; } pk;
      pk.q[0] = packbf4(h[0], h[1], h[2], h[3]);
      pk.q[1] = packbf4(h[4], h[5], h[6], h[7]);
      uint64_t hw = (uint64_t)((char*)hbf + (size_t)((t + 1) & 1) * (BATCH * (HID / 4) * 8) + hoff * 8);
      asm volatile("global_store_dwordx4 %0, %1, off sc0 sc1" :: "v"(hw), "v"(pk.v4) : "memory");
      BARRIER_ARRIVE(t + 2);
      LOAD_XW(t + 1);   // prefetch next step's gate inputs under the barrier wait
      BARRIER_WAIT(t + 2);
    }
  }

  #pragma unroll
  for (int j = 0; j < 8; ++j)
    hf32[(size_t)gb * HID + U0 + j0 + j] = h[j];
}

// ---------------- head: logits = tanh(h @ p1^T + b1) @ p2^T + b2 ----------------
__global__ __launch_bounds__(256) void head_kernel(
    const float* __restrict__ hf32, const float* __restrict__ p1W,
    const float* __restrict__ p1b, const float* __restrict__ p2W,
    const float* __restrict__ p2b, float* __restrict__ outp)
{
  int b = blockIdx.x;
  int tid = threadIdx.x;
  __shared__ float hrow[HID];
  __shared__ float red[4][64];
  __shared__ float s1[64];
  for (int d = tid; d < HID; d += 256) hrow[d] = hf32[(long)b * HID + d];
  __syncthreads();
  int j = tid & 63, q = tid >> 6;
  const float* wrow = p1W + (long)j * HID + q * 256;
  float s = 0.0f;
  for (int k = 0; k < 256; ++k) s += hrow[q * 256 + k] * wrow[k];
  red[q][j] = s;
  __syncthreads();
  if (tid < 64) {
    float v = red[0][tid] + red[1][tid] + red[2][tid] + red[3][tid] + p1b[tid];
    s1[tid] = tanh_fast(v);
  }
  __syncthreads();
  if (tid < 2) {
    float a = p2b[tid];
    for (int k = 0; k < 64; ++k) a += s1[k] * p2W[tid * 64 + k];
    outp[b * 2 + tid] = a;
  }
}

// ---------------- launch ----------------
extern "C" void kernel_launch(void* const* d_in, const int* in_sizes, int n_in,
                              void* d_out, int out_size, void* d_ws, size_t ws_size,
                              hipStream_t stream) {
  const int*   tgt_ids = (const int*)d_in[0];
  const int*   tgt_len = (const int*)d_in[1];
  const int*   src_ids = (const int*)d_in[2];
  const int*   src_len = (const int*)d_in[3];
  const float* emb  = (const float*)d_in[6];
  const float* sWih = (const float*)d_in[7];
  const float* sWhh = (const float*)d_in[8];
  const float* sbih = (const float*)d_in[9];
  const float* sbhh = (const float*)d_in[10];
  const float* tWih = (const float*)d_in[11];
  const float* tWhh = (const float*)d_in[12];
  const float* tbih = (const float*)d_in[13];
  const float* tbhh = (const float*)d_in[14];
  const float* p1W  = (const float*)d_in[19];
  const float* p1b  = (const float*)d_in[20];
  const float* p2W  = (const float*)d_in[21];
  const float* p2b  = (const float*)d_in[22];

  char* ws = (char*)d_ws;
  size_t off = 0;
  float* xw = (float*)(ws + off);                   off += (size_t)MROWS * G3 * 4;
  unsigned short* X  = (unsigned short*)(ws + off); off += (size_t)MROWS * DIM * 2;
  unsigned short* Wb = (unsigned short*)(ws + off); off += (size_t)G3 * DIM * 2;
  u64* hbf = (u64*)(ws + off);                      off += 2ull * BATCH * (HID / 4) * 8;
  float* hf32 = (float*)(ws + off);                 off += (size_t)BATCH * HID * 4;
  unsigned int* bars = (unsigned int*)(ws + off);   off += 4096;   // 2 flag regions (64B-strided)
  if (ws_size < off) return;

  const int PREP_BLOCKS = MROWS + G3;  // 11264

  // src pipeline
  prep_kernel<<<PREP_BLOCKS, 256, 0, stream>>>(src_ids, emb, sWih, X, Wb, bars);
  xw_gemm<<<dim3(G3 / BN, MROWS / BM), 256, 0, stream>>>(X, Wb, sbih, xw);
  gru_kernel<<<NB, 256, 0, stream>>>(sWhh, sbhh, xw, src_len, hbf, hf32, bars, TSEQ, 1);
  // tgt pipeline (h0 = src final hidden in hf32)
  prep_kernel<<<PREP_BLOCKS, 256, 0, stream>>>(tgt_ids, emb, tWih, X, Wb, nullptr);
  xw_gemm<<<dim3(G3 / BN, MROWS / BM), 256, 0, stream>>>(X, Wb, tbih, xw);
  gru_kernel<<<NB, 256, 0, stream>>>(tWhh, tbhh, xw, tgt_len, hbf, hf32, bars + 512, TSEQ, 0);
  // head
  head_kernel<<<BATCH, 256, 0, stream>>>(hf32, p1W, p1b, p2W, p2b, (float*)d_out);
}